// Round 3
// baseline (848.686 us; speedup 1.0000x reference)
//
#include <hip/hip_runtime.h>
#include <hip/hip_bf16.h>

#define Bb 2
#define Tt 2048
#define DIMd 1024
#define Hh 16
#define HDh 64
#define MTOK (Bb * Tt)
#define NSCALE 0.03125f   // 1/sqrt(1024)

typedef __attribute__((ext_vector_type(8))) short bf16x8;
typedef __attribute__((ext_vector_type(4))) float floatx4;

__device__ __forceinline__ unsigned short f2bf(float f) {
    union { float f; unsigned int u; } a; a.f = f;
    const unsigned int u = a.u;
    return (unsigned short)((u + 0x7FFFu + ((u >> 16) & 1u)) >> 16);  // RNE
}

__device__ __forceinline__ void gl_lds16(const void* g, void* l) {
    __builtin_amdgcn_global_load_lds((const __attribute__((address_space(1))) void*)g,
                                     (__attribute__((address_space(3))) void*)l, 16, 0, 0);
}

// ---------------- fp32 -> bf16 convert, all 7 inputs in one launch ----------------
__global__ __launch_bounds__(256) void cvt_all(
    const float* __restrict__ s0, const float* __restrict__ s1, const float* __restrict__ s2,
    const float* __restrict__ s3, const float* __restrict__ s4, const float* __restrict__ s5,
    const float* __restrict__ s6,
    unsigned short* __restrict__ d0, unsigned short* __restrict__ d1, unsigned short* __restrict__ d2,
    unsigned short* __restrict__ d3, unsigned short* __restrict__ d4, unsigned short* __restrict__ d5,
    unsigned short* __restrict__ d6) {
    const int blk = blockIdx.x;
    const float* src; unsigned short* dst; int rb;
    if (blk < 12288) {
        const int r = blk >> 12;          // 0..2
        rb  = blk & 4095;
        src = (r == 0) ? s0 : ((r == 1) ? s1 : s2);
        dst = (r == 0) ? d0 : ((r == 1) ? d1 : d2);
    } else {
        const int r = (blk - 12288) >> 10; // 0..3
        rb  = blk & 1023;
        src = (r == 0) ? s3 : ((r == 1) ? s4 : ((r == 2) ? s5 : s6));
        dst = (r == 0) ? d3 : ((r == 1) ? d4 : ((r == 2) ? d5 : d6));
    }
    const int i = (rb * 256 + threadIdx.x) * 4;
    const float4 v = *(const float4*)(src + i);
    ushort4 o;
    o.x = f2bf(v.x); o.y = f2bf(v.y); o.z = f2bf(v.z); o.w = f2bf(v.w);
    *(ushort4*)(dst + i) = o;
}

// ---------------- bf16 MFMA GEMM tile:  C[m,n] = sum_k A[m,k] * W[n,k] ----------------
// 128x128 tile, BK=64, XOR-swizzled LDS (both-sides: pre-swizzled global source +
// swizzled ds_read), global_load_lds width-16 staging. 4 waves (2x2), 4x4 MFMA each.
template <int BF16OUT>
__device__ __forceinline__ void gemm_tile(unsigned short* As, unsigned short* Bs,
                                          const unsigned short* __restrict__ A,
                                          const unsigned short* __restrict__ W,
                                          void* __restrict__ Cv,
                                          int N, int K, int m0, int n0) {
    const int tid  = threadIdx.x;
    const int wave = tid >> 6;
    const int lane = tid & 63;
    const int wm = (wave >> 1) * 64;
    const int wn = (wave & 1) * 64;
    const int qd = lane >> 4;       // 0..3
    const int ln16 = lane & 15;
    const int x7 = ln16 & 7;

    floatx4 acc[4][4];
#pragma unroll
    for (int mi = 0; mi < 4; ++mi)
#pragma unroll
        for (int ni = 0; ni < 4; ++ni) acc[mi][ni] = (floatx4){0.f, 0.f, 0.f, 0.f};

    for (int k0 = 0; k0 < K; k0 += 64) {
        // stage 128x64 bf16 tiles: 1024 chunks of 16B each; chunk c -> row c>>3,
        // swizzled col slot (c&7)^(row&7). LDS linear, SOURCE pre-swizzled.
#pragma unroll
        for (int t = 0; t < 4; ++t) {
            const int c   = t * 256 + wave * 64 + lane;
            const int row = c >> 3;
            const int col = ((c & 7) ^ (row & 7)) * 8;
            gl_lds16(A + (size_t)(m0 + row) * K + k0 + col, &As[c * 8]);
            gl_lds16(W + (size_t)(n0 + row) * K + k0 + col, &Bs[c * 8]);
        }
        __syncthreads();   // drains vmcnt(0): tiles resident

#pragma unroll
        for (int ks = 0; ks < 2; ++ks) {
            bf16x8 af[4], bfr[4];
#pragma unroll
            for (int mi = 0; mi < 4; ++mi)
                af[mi] = *(const bf16x8*)&As[(wm + mi * 16 + ln16) * 64 + (((ks * 4 + qd) ^ x7) * 8)];
#pragma unroll
            for (int ni = 0; ni < 4; ++ni)
                bfr[ni] = *(const bf16x8*)&Bs[(wn + ni * 16 + ln16) * 64 + (((ks * 4 + qd) ^ x7) * 8)];
            __builtin_amdgcn_s_setprio(1);
#pragma unroll
            for (int mi = 0; mi < 4; ++mi)
#pragma unroll
                for (int ni = 0; ni < 4; ++ni)
                    acc[mi][ni] = __builtin_amdgcn_mfma_f32_16x16x32_bf16(af[mi], bfr[ni], acc[mi][ni], 0, 0, 0);
            __builtin_amdgcn_s_setprio(0);
        }
        __syncthreads();   // protect LDS before next stage
    }

    // C/D layout: col = lane&15, row = (lane>>4)*4 + reg
#pragma unroll
    for (int mi = 0; mi < 4; ++mi)
#pragma unroll
        for (int ni = 0; ni < 4; ++ni) {
            const int gn = n0 + wn + ni * 16 + ln16;
#pragma unroll
            for (int r = 0; r < 4; ++r) {
                const int gm = m0 + wm + mi * 16 + qd * 4 + r;
                if (BF16OUT)
                    ((unsigned short*)Cv)[(size_t)gm * N + gn] = f2bf(acc[mi][ni][r]);
                else
                    ((float*)Cv)[(size_t)gm * N + gn] = acc[mi][ni][r];
            }
        }
}

// ---------------- 3 projection GEMMs in one launch (768 blocks -> 3 blocks/CU) ----
// z0: qp = Qb @ Wq^T (4096x1024), z1: kp = Kb @ Wk^T (4096x1024),
// z2: vt = Wv @ Vb^T (1024x4096, i.e. V-projection TRANSPOSED).
__global__ __launch_bounds__(256) void gemm_proj3(
    const unsigned short* __restrict__ Qb, const unsigned short* __restrict__ Wqb, unsigned short* __restrict__ qp,
    const unsigned short* __restrict__ Kb, const unsigned short* __restrict__ Wkb, unsigned short* __restrict__ kp,
    const unsigned short* __restrict__ Vb, const unsigned short* __restrict__ Wvb, unsigned short* __restrict__ vt) {
    __shared__ unsigned short As[128 * 64];
    __shared__ unsigned short Bs[128 * 64];
    const int bid = blockIdx.x;
    if (bid < 256) {
        gemm_tile<1>(As, Bs, Qb, Wqb, qp, DIMd, DIMd, (bid >> 3) * 128, (bid & 7) * 128);
    } else if (bid < 512) {
        const int r = bid - 256;
        gemm_tile<1>(As, Bs, Kb, Wkb, kp, DIMd, DIMd, (r >> 3) * 128, (r & 7) * 128);
    } else {
        const int r = bid - 512;
        gemm_tile<1>(As, Bs, Wvb, Vb, vt, MTOK, DIMd, (r >> 5) * 128, (r & 31) * 128);
    }
}

// ---------------- Wo GEMM + att rescale merged (compute + memory co-resident) ----
// blocks [0,256): y = ymid @ Wo^T. blocks [256, 256+4096): 16 att rows each:
// att[i,j] = j<=i ? att[i,j]/l[i] : 0.
__global__ __launch_bounds__(256) void gemm_o_rescale(const unsigned short* __restrict__ ymid,
                                                      const unsigned short* __restrict__ Wob,
                                                      float* __restrict__ y,
                                                      float* __restrict__ att,
                                                      const float* __restrict__ lws) {
    __shared__ unsigned short As[128 * 64];
    __shared__ unsigned short Bs[128 * 64];
    const int bid = blockIdx.x;
    if (bid < 256) {
        gemm_tile<0>(As, Bs, ymid, Wob, y, DIMd, DIMd, (bid >> 3) * 128, (bid & 7) * 128);
        return;
    }
    const int rb  = bid - 256;      // 0..4095
    const int tid = threadIdx.x;
#pragma unroll
    for (int rr = 0; rr < 16; ++rr) {
        const int row = rb * 16 + rr;
        const int i   = row & (Tt - 1);
        const float inv = 1.f / lws[row];
        float4* arow = (float4*)(att + (size_t)row * Tt);
#pragma unroll
        for (int q = 0; q < 2; ++q) {
            const int f4 = tid + q * 256;
            const int j  = f4 * 4;
            float4 v;
            if (j <= i) {
                v = arow[f4];
                v.x = (j + 0 <= i) ? v.x * inv : 0.f;
                v.y = (j + 1 <= i) ? v.y * inv : 0.f;
                v.z = (j + 2 <= i) ? v.z * inv : 0.f;
                v.w = (j + 3 <= i) ? v.w * inv : 0.f;
            } else {
                v = make_float4(0.f, 0.f, 0.f, 0.f);
            }
            arow[f4] = v;
        }
    }
}

// ---------------- fused causal attention, MFMA bf16, swapped QK^T ----------------
#define PSTR 72   // Ps row stride in shorts (pad to dodge bank conflicts)

__global__ __launch_bounds__(256) void fused_attn(const unsigned short* __restrict__ qp,
                                                  const unsigned short* __restrict__ kp,
                                                  const unsigned short* __restrict__ vt,
                                                  float* __restrict__ att,
                                                  unsigned short* __restrict__ ymid,
                                                  float* __restrict__ lws) {
    __shared__ unsigned short Ks[64 * 64];   // [key][dim], chunk-swizzled
    __shared__ unsigned short Vs[64 * 64];   // [dim][key], chunk-swizzled
    __shared__ unsigned short Ps[64 * PSTR]; // per-wave 16-row chunks [query][key]

    const int bid = blockIdx.x;
    const int bh  = bid & 31;
    const int it  = 31 - (bid >> 5);          // long rows first
    const int h   = bh & (Hh - 1);
    const int b   = bh >> 4;
    const int tid  = threadIdx.x;
    const int w    = tid >> 6;
    const int lane = tid & 63;
    const int qd   = lane >> 4;               // 0..3
    const int ln16 = lane & 15;
    const int i0   = it * 64;
    const int ig   = i0 + w * 16 + ln16;      // this lane's global query row

    // Q fragments (B-operand): lane ln16 <-> query, chunk qd
    bf16x8 qf[2];
    {
        const unsigned short* qrow = qp + (size_t)(b * Tt + ig) * DIMd + h * HDh;
        qf[0] = *(const bf16x8*)(qrow + qd * 8);
        qf[1] = *(const bf16x8*)(qrow + 32 + qd * 8);
    }

    floatx4 oacc[4];
#pragma unroll
    for (int dt = 0; dt < 4; ++dt) oacc[dt] = (floatx4){0.f, 0.f, 0.f, 0.f};
    float lsum = 0.f;

    unsigned short* Pw = &Ps[w * 16 * PSTR];
    float* arow = att + ((size_t)bh * Tt + ig) * Tt;

    for (int jt = 0; jt <= it; ++jt) {
        const int j0 = jt * 64;
        __syncthreads();   // prev-iter LDS reads done

        // stage K and Vt tiles (bf16, 8 KB each); LDS linear, SOURCE pre-swizzled.
#pragma unroll
        for (int t = 0; t < 2; ++t) {
            const int c   = w * 128 + t * 64 + lane;
            const int row = c >> 3;
            const int cb  = c & 7;
            const int col8 = ((cb ^ (row & 7)) * 8);
            gl_lds16(kp + (size_t)(b * Tt + j0 + row) * DIMd + h * HDh + col8, &Ks[c * 8]);
            gl_lds16(vt + (size_t)(h * HDh + row) * MTOK + b * Tt + j0 + col8, &Vs[c * 8]);
        }
        __syncthreads();   // tiles resident

        // ---- QK^T (swapped): lane holds query ln16, keys ct*16+qd*4+r ----
        floatx4 sacc[4];
#pragma unroll
        for (int ct = 0; ct < 4; ++ct) sacc[ct] = (floatx4){0.f, 0.f, 0.f, 0.f};
        __builtin_amdgcn_s_setprio(1);
#pragma unroll
        for (int ks = 0; ks < 2; ++ks)
#pragma unroll
            for (int ct = 0; ct < 4; ++ct) {
                const int row = ct * 16 + ln16;
                const bf16x8 kf = *(const bf16x8*)&Ks[row * 64 + (((ks * 4 + qd) ^ (row & 7)) * 8)];
                sacc[ct] = __builtin_amdgcn_mfma_f32_16x16x32_bf16(kf, qf[ks], sacc[ct], 0, 0, 0);
            }
        __builtin_amdgcn_s_setprio(0);

        // ---- exp + mask; float4 att store; b64 P write; 2-shfl rowsum ----
        float rs = 0.f;
#pragma unroll
        for (int ct = 0; ct < 4; ++ct) {
            const int jb = j0 + ct * 16 + qd * 4;
            float4 ev;
            {
                const float e0 = (jb + 0 <= ig) ? __expf(sacc[ct][0] * NSCALE) : 0.f;
                const float e1 = (jb + 1 <= ig) ? __expf(sacc[ct][1] * NSCALE) : 0.f;
                const float e2 = (jb + 2 <= ig) ? __expf(sacc[ct][2] * NSCALE) : 0.f;
                const float e3 = (jb + 3 <= ig) ? __expf(sacc[ct][3] * NSCALE) : 0.f;
                ev = make_float4(e0, e1, e2, e3);
                rs += e0 + e1 + e2 + e3;
            }
            *(float4*)(arow + jb) = ev;
            ushort4 pk;
            pk.x = f2bf(ev.x); pk.y = f2bf(ev.y); pk.z = f2bf(ev.z); pk.w = f2bf(ev.w);
            *(ushort4*)&Pw[ln16 * PSTR + ct * 16 + qd * 4] = pk;
        }
        rs += __shfl_xor(rs, 16);
        rs += __shfl_xor(rs, 32);
        lsum += rs;

        // ---- PV: O[16 x 64] += P(16x64) @ V(64x64) ----
        __builtin_amdgcn_s_setprio(1);
#pragma unroll
        for (int ks = 0; ks < 2; ++ks) {
            const bf16x8 pf = *(const bf16x8*)&Pw[ln16 * PSTR + ks * 32 + qd * 8];
#pragma unroll
            for (int dt = 0; dt < 4; ++dt) {
                const int row = dt * 16 + ln16;
                const bf16x8 vf = *(const bf16x8*)&Vs[row * 64 + (((ks * 4 + qd) ^ (row & 7)) * 8)];
                oacc[dt] = __builtin_amdgcn_mfma_f32_16x16x32_bf16(pf, vf, oacc[dt], 0, 0, 0);
            }
        }
        __builtin_amdgcn_s_setprio(0);
    }

    // ---- epilogue: fetch row sums via shuffle, normalize, write ymid + lws ----
    float lssrc[4];
#pragma unroll
    for (int r = 0; r < 4; ++r) lssrc[r] = __shfl(lsum, qd * 4 + r);
#pragma unroll
    for (int r = 0; r < 4; ++r) {
        const float inv = 1.f / lssrc[r];
        unsigned short* yr = ymid + (size_t)(b * Tt + i0 + w * 16 + qd * 4 + r) * DIMd + h * HDh + ln16;
#pragma unroll
        for (int dt = 0; dt < 4; ++dt)
            yr[dt * 16] = f2bf(oacc[dt][r] * inv);
    }
    if (qd == 0) lws[(size_t)bh * Tt + ig] = lsum;
}

extern "C" void kernel_launch(void* const* d_in, const int* in_sizes, int n_in,
                              void* d_out, int out_size, void* d_ws, size_t ws_size,
                              hipStream_t stream) {
    const float* Q  = (const float*)d_in[0];
    const float* K  = (const float*)d_in[1];
    const float* V  = (const float*)d_in[2];
    const float* Wq = (const float*)d_in[3];
    const float* Wk = (const float*)d_in[4];
    const float* Wv = (const float*)d_in[5];
    const float* Wo = (const float*)d_in[6];

    const size_t nytok = (size_t)Bb * Tt * DIMd;   // 4,194,304
    const size_t nw    = (size_t)DIMd * DIMd;      // 1,048,576
    float* y   = (float*)d_out;
    float* att = y + nytok;

    char* w = (char*)d_ws;
    unsigned short* qp  = (unsigned short*)w;    w += nytok * 2;   // bf16 Q-proj
    unsigned short* kp  = (unsigned short*)w;    w += nytok * 2;   // bf16 K-proj
    unsigned short* vt  = (unsigned short*)w;    w += nytok * 2;   // bf16 V-proj, TRANSPOSED [DIM][B*T]
    unsigned short* Qb  = (unsigned short*)w;    w += nytok * 2;   // reused as ymid_b
    unsigned short* Kb  = (unsigned short*)w;    w += nytok * 2;
    unsigned short* Vb  = (unsigned short*)w;    w += nytok * 2;
    unsigned short* Wqb = (unsigned short*)w;    w += nw * 2;
    unsigned short* Wkb = (unsigned short*)w;    w += nw * 2;
    unsigned short* Wvb = (unsigned short*)w;    w += nw * 2;
    unsigned short* Wob = (unsigned short*)w;    w += nw * 2;
    float* lws = (float*)w;
    unsigned short* ymid_b = Qb;

    cvt_all<<<16384, 256, 0, stream>>>(Q, K, V, Wq, Wk, Wv, Wo,
                                       Qb, Kb, Vb, Wqb, Wkb, Wvb, Wob);

    gemm_proj3<<<768, 256, 0, stream>>>(Qb, Wqb, qp, Kb, Wkb, kp, Vb, Wvb, vt);

    fused_attn<<<32 * 32, 256, 0, stream>>>(qp, kp, vt, att, ymid_b, lws);

    gemm_o_rescale<<<256 + 4096, 256, 0, stream>>>(ymid_b, Wob, y, att, lws);
}

// Round 4
// 711.516 us; speedup vs baseline: 1.1928x; 1.1928x over previous
//
#include <hip/hip_runtime.h>
#include <hip/hip_bf16.h>

#define Bb 2
#define Tt 2048
#define DIMd 1024
#define Hh 16
#define HDh 64
#define MTOK (Bb * Tt)
#define NSCALE 0.03125f   // 1/sqrt(1024)

typedef __attribute__((ext_vector_type(8))) short bf16x8;
typedef __attribute__((ext_vector_type(4))) float floatx4;

__device__ __forceinline__ unsigned short f2bf(float f) {
    union { float f; unsigned int u; } a; a.f = f;
    const unsigned int u = a.u;
    return (unsigned short)((u + 0x7FFFu + ((u >> 16) & 1u)) >> 16);  // RNE
}

__device__ __forceinline__ void gl_lds16(const void* g, void* l) {
    __builtin_amdgcn_global_load_lds((const __attribute__((address_space(1))) void*)g,
                                     (__attribute__((address_space(3))) void*)l, 16, 0, 0);
}

// ---------------- fp32 -> bf16 convert, all 7 inputs in one launch ----------------
__global__ __launch_bounds__(256) void cvt_all(
    const float* __restrict__ s0, const float* __restrict__ s1, const float* __restrict__ s2,
    const float* __restrict__ s3, const float* __restrict__ s4, const float* __restrict__ s5,
    const float* __restrict__ s6,
    unsigned short* __restrict__ d0, unsigned short* __restrict__ d1, unsigned short* __restrict__ d2,
    unsigned short* __restrict__ d3, unsigned short* __restrict__ d4, unsigned short* __restrict__ d5,
    unsigned short* __restrict__ d6) {
    const int blk = blockIdx.x;
    const float* src; unsigned short* dst; int rb;
    if (blk < 12288) {
        const int r = blk >> 12;          // 0..2
        rb  = blk & 4095;
        src = (r == 0) ? s0 : ((r == 1) ? s1 : s2);
        dst = (r == 0) ? d0 : ((r == 1) ? d1 : d2);
    } else {
        const int r = (blk - 12288) >> 10; // 0..3
        rb  = blk & 1023;
        src = (r == 0) ? s3 : ((r == 1) ? s4 : ((r == 2) ? s5 : s6));
        dst = (r == 0) ? d3 : ((r == 1) ? d4 : ((r == 2) ? d5 : d6));
    }
    const int i = (rb * 256 + threadIdx.x) * 4;
    const float4 v = *(const float4*)(src + i);
    ushort4 o;
    o.x = f2bf(v.x); o.y = f2bf(v.y); o.z = f2bf(v.z); o.w = f2bf(v.w);
    *(ushort4*)(dst + i) = o;
}

// ---------------- bf16 MFMA GEMM tile (m97/R2-verified BK=32 structure) ----------
// C[m,n] = sum_k A[m,k] * W[n,k]; 128x128 tile, BK=32, 4 waves (2x2), 4x4 MFMA.
template <int BF16OUT>
__device__ __forceinline__ void gemm_tile32(unsigned short* As, unsigned short* Bs,
                                            const unsigned short* __restrict__ A,
                                            const unsigned short* __restrict__ W,
                                            void* __restrict__ Cv,
                                            int N, int K, int m0, int n0) {
    const int tid  = threadIdx.x;
    const int wave = tid >> 6;
    const int lane = tid & 63;
    const int wm = (wave >> 1) * 64;
    const int wn = (wave & 1) * 64;
    const int qd = lane >> 4;       // 0..3
    const int ln16 = lane & 15;

    floatx4 acc[4][4];
#pragma unroll
    for (int mi = 0; mi < 4; ++mi)
#pragma unroll
        for (int ni = 0; ni < 4; ++ni) acc[mi][ni] = (floatx4){0.f, 0.f, 0.f, 0.f};

    for (int k0 = 0; k0 < K; k0 += 32) {
#pragma unroll
        for (int t = 0; t < 2; ++t) {
            const int c = t * 256 + wave * 64 + lane;
            const int row = c >> 2;
            const int col = (c & 3) * 8;
            gl_lds16(A + (size_t)(m0 + row) * K + k0 + col, &As[c * 8]);
            gl_lds16(W + (size_t)(n0 + row) * K + k0 + col, &Bs[c * 8]);
        }
        __syncthreads();   // drains vmcnt(0): tiles resident

        bf16x8 af[4], bfr[4];
#pragma unroll
        for (int mi = 0; mi < 4; ++mi)
            af[mi] = *(const bf16x8*)&As[(wm + mi * 16 + ln16) * 32 + qd * 8];
#pragma unroll
        for (int ni = 0; ni < 4; ++ni)
            bfr[ni] = *(const bf16x8*)&Bs[(wn + ni * 16 + ln16) * 32 + qd * 8];
#pragma unroll
        for (int mi = 0; mi < 4; ++mi)
#pragma unroll
            for (int ni = 0; ni < 4; ++ni)
                acc[mi][ni] = __builtin_amdgcn_mfma_f32_16x16x32_bf16(af[mi], bfr[ni], acc[mi][ni], 0, 0, 0);
        __syncthreads();   // protect LDS before next stage
    }

    // C/D layout: col = lane&15, row = (lane>>4)*4 + reg
#pragma unroll
    for (int mi = 0; mi < 4; ++mi)
#pragma unroll
        for (int ni = 0; ni < 4; ++ni) {
            const int gn = n0 + wn + ni * 16 + ln16;
#pragma unroll
            for (int r = 0; r < 4; ++r) {
                const int gm = m0 + wm + mi * 16 + qd * 4 + r;
                if (BF16OUT)
                    ((unsigned short*)Cv)[(size_t)gm * N + gn] = f2bf(acc[mi][ni][r]);
                else
                    ((float*)Cv)[(size_t)gm * N + gn] = acc[mi][ni][r];
            }
        }
}

// ---------------- 3 projection GEMMs in one launch (768 blocks -> 3 blocks/CU) ----
__global__ __launch_bounds__(256) void gemm_proj3(
    const unsigned short* __restrict__ Qb, const unsigned short* __restrict__ Wqb, unsigned short* __restrict__ qp,
    const unsigned short* __restrict__ Kb, const unsigned short* __restrict__ Wkb, unsigned short* __restrict__ kp,
    const unsigned short* __restrict__ Vb, const unsigned short* __restrict__ Wvb, unsigned short* __restrict__ vt) {
    __shared__ unsigned short As[128 * 32];
    __shared__ unsigned short Bs[128 * 32];
    const int bid = blockIdx.x;
    if (bid < 256) {
        gemm_tile32<1>(As, Bs, Qb, Wqb, qp, DIMd, DIMd, (bid >> 3) * 128, (bid & 7) * 128);
    } else if (bid < 512) {
        const int r = bid - 256;
        gemm_tile32<1>(As, Bs, Kb, Wkb, kp, DIMd, DIMd, (r >> 3) * 128, (r & 7) * 128);
    } else {
        const int r = bid - 512;
        gemm_tile32<1>(As, Bs, Wvb, Vb, vt, MTOK, DIMd, (r >> 5) * 128, (r & 31) * 128);
    }
}

// ---------------- fused causal attention, MFMA bf16, swapped QK^T ----------------
// No att store anymore: only ymid (normalized PV output, bf16) + lws (row sums).
#define PSTR 72   // Ps row stride in shorts (pad to dodge bank conflicts)

__global__ __launch_bounds__(256) void fused_attn(const unsigned short* __restrict__ qp,
                                                  const unsigned short* __restrict__ kp,
                                                  const unsigned short* __restrict__ vt,
                                                  unsigned short* __restrict__ ymid,
                                                  float* __restrict__ lws) {
    __shared__ unsigned short Ks[64 * 64];   // [key][dim], chunk-swizzled
    __shared__ unsigned short Vs[64 * 64];   // [dim][key], chunk-swizzled
    __shared__ unsigned short Ps[64 * PSTR]; // per-wave 16-row chunks [query][key]

    const int bid = blockIdx.x;
    const int bh  = bid & 31;
    const int it  = 31 - (bid >> 5);          // long rows first
    const int h   = bh & (Hh - 1);
    const int b   = bh >> 4;
    const int tid  = threadIdx.x;
    const int w    = tid >> 6;
    const int lane = tid & 63;
    const int qd   = lane >> 4;               // 0..3
    const int ln16 = lane & 15;
    const int i0   = it * 64;
    const int ig   = i0 + w * 16 + ln16;      // this lane's global query row

    // Q fragments (B-operand): lane ln16 <-> query, chunk qd
    bf16x8 qf[2];
    {
        const unsigned short* qrow = qp + (size_t)(b * Tt + ig) * DIMd + h * HDh;
        qf[0] = *(const bf16x8*)(qrow + qd * 8);
        qf[1] = *(const bf16x8*)(qrow + 32 + qd * 8);
    }

    floatx4 oacc[4];
#pragma unroll
    for (int dt = 0; dt < 4; ++dt) oacc[dt] = (floatx4){0.f, 0.f, 0.f, 0.f};
    float lsum = 0.f;

    unsigned short* Pw = &Ps[w * 16 * PSTR];

    for (int jt = 0; jt <= it; ++jt) {
        const int j0 = jt * 64;
        __syncthreads();   // prev-iter LDS reads done

        // stage K and Vt tiles (bf16, 8 KB each); LDS linear, SOURCE pre-swizzled.
#pragma unroll
        for (int t = 0; t < 2; ++t) {
            const int c   = w * 128 + t * 64 + lane;
            const int row = c >> 3;
            const int cb  = c & 7;
            const int col8 = ((cb ^ (row & 7)) * 8);
            gl_lds16(kp + (size_t)(b * Tt + j0 + row) * DIMd + h * HDh + col8, &Ks[c * 8]);
            gl_lds16(vt + (size_t)(h * HDh + row) * MTOK + b * Tt + j0 + col8, &Vs[c * 8]);
        }
        __syncthreads();   // tiles resident

        // ---- QK^T (swapped): lane holds query ln16, keys ct*16+qd*4+r ----
        floatx4 sacc[4];
#pragma unroll
        for (int ct = 0; ct < 4; ++ct) sacc[ct] = (floatx4){0.f, 0.f, 0.f, 0.f};
        __builtin_amdgcn_s_setprio(1);
#pragma unroll
        for (int ks = 0; ks < 2; ++ks)
#pragma unroll
            for (int ct = 0; ct < 4; ++ct) {
                const int row = ct * 16 + ln16;
                const bf16x8 kf = *(const bf16x8*)&Ks[row * 64 + (((ks * 4 + qd) ^ (row & 7)) * 8)];
                sacc[ct] = __builtin_amdgcn_mfma_f32_16x16x32_bf16(kf, qf[ks], sacc[ct], 0, 0, 0);
            }
        __builtin_amdgcn_s_setprio(0);

        // ---- exp + mask; b64 P write; 2-shfl rowsum ----
        float rs = 0.f;
#pragma unroll
        for (int ct = 0; ct < 4; ++ct) {
            const int jb = j0 + ct * 16 + qd * 4;
            const float e0 = (jb + 0 <= ig) ? __expf(sacc[ct][0] * NSCALE) : 0.f;
            const float e1 = (jb + 1 <= ig) ? __expf(sacc[ct][1] * NSCALE) : 0.f;
            const float e2 = (jb + 2 <= ig) ? __expf(sacc[ct][2] * NSCALE) : 0.f;
            const float e3 = (jb + 3 <= ig) ? __expf(sacc[ct][3] * NSCALE) : 0.f;
            rs += e0 + e1 + e2 + e3;
            ushort4 pk;
            pk.x = f2bf(e0); pk.y = f2bf(e1); pk.z = f2bf(e2); pk.w = f2bf(e3);
            *(ushort4*)&Pw[ln16 * PSTR + ct * 16 + qd * 4] = pk;
        }
        rs += __shfl_xor(rs, 16);
        rs += __shfl_xor(rs, 32);
        lsum += rs;

        // ---- PV: O[16 x 64] += P(16x64) @ V(64x64) ----
        __builtin_amdgcn_s_setprio(1);
#pragma unroll
        for (int ks = 0; ks < 2; ++ks) {
            const bf16x8 pf = *(const bf16x8*)&Pw[ln16 * PSTR + ks * 32 + qd * 8];
#pragma unroll
            for (int dt = 0; dt < 4; ++dt) {
                const int row = dt * 16 + ln16;
                const bf16x8 vf = *(const bf16x8*)&Vs[row * 64 + (((ks * 4 + qd) ^ (row & 7)) * 8)];
                oacc[dt] = __builtin_amdgcn_mfma_f32_16x16x32_bf16(pf, vf, oacc[dt], 0, 0, 0);
            }
        }
        __builtin_amdgcn_s_setprio(0);
    }

    // ---- epilogue: fetch row sums via shuffle, normalize, write ymid + lws ----
    float lssrc[4];
#pragma unroll
    for (int r = 0; r < 4; ++r) lssrc[r] = __shfl(lsum, qd * 4 + r);
#pragma unroll
    for (int r = 0; r < 4; ++r) {
        const float inv = 1.f / lssrc[r];
        unsigned short* yr = ymid + (size_t)(b * Tt + i0 + w * 16 + qd * 4 + r) * DIMd + h * HDh + ln16;
#pragma unroll
        for (int dt = 0; dt < 4; ++dt)
            yr[dt * 16] = f2bf(oacc[dt][r] * inv);
    }
    if (qd == 0) lws[(size_t)bh * Tt + ig] = lsum;
}

// ---------------- Wo GEMM + normalized-att writer in one launch ----------------
// blocks [0,256): y = ymid @ Wo^T.
// blocks [256, 256+8192): one 128x128 att tile each (32 bh x 16 x 16 tiles):
//   upper (tj>ti): write zeros; lower/diag: recompute S = QK^T via MFMA (identical
//   fragment/accumulation order as fused_attn -> bit-identical), write
//   att[i][j] = exp(s*NSCALE) * (1/l[i]) with causal mask on the diagonal tile.
__global__ __launch_bounds__(256) void gemm_o_attw(const unsigned short* __restrict__ ymid,
                                                   const unsigned short* __restrict__ Wob,
                                                   float* __restrict__ y,
                                                   const unsigned short* __restrict__ qp,
                                                   const unsigned short* __restrict__ kp,
                                                   const float* __restrict__ lws,
                                                   float* __restrict__ att) {
    __shared__ unsigned short smem[128 * 64];   // GEMM: As|Bs (8KB each); att: Ks tile

    const int bid = blockIdx.x;
    if (bid < 256) {
        gemm_tile32<0>(smem, smem + 128 * 32, ymid, Wob, y, DIMd, DIMd,
                       (bid >> 3) * 128, (bid & 7) * 128);
        return;
    }
    const int ab = bid - 256;          // 0..8191
    const int bh = ab >> 8;            // 0..31
    const int t  = ab & 255;
    const int ti = t >> 4;
    const int tj = t & 15;
    const int h  = bh & (Hh - 1);
    const int b  = bh >> 4;
    const int tid = threadIdx.x;
    const int i0 = ti * 128;
    const int j0 = tj * 128;
    float* abase = att + (size_t)bh * Tt * Tt;

    if (tj > ti) {   // strictly-upper tile: zeros, pure stream
        const float4 z = make_float4(0.f, 0.f, 0.f, 0.f);
#pragma unroll
        for (int k = 0; k < 16; ++k) {
            const int f   = k * 256 + tid;
            const int row = f >> 5;
            const int c4  = f & 31;
            *(float4*)(abase + (size_t)(i0 + row) * Tt + j0 + c4 * 4) = z;
        }
        return;
    }

    const int w    = tid >> 6;
    const int lane = tid & 63;
    const int qd   = lane >> 4;
    const int ln16 = lane & 15;
    const int wm   = (w >> 1) * 64;    // query offset in tile
    const int wn   = (w & 1) * 64;     // key offset in tile

    // stage K tile 128x64 bf16 (chunk-swizzled, linear LDS dest)
#pragma unroll
    for (int t4 = 0; t4 < 4; ++t4) {
        const int c   = t4 * 256 + tid;
        const int row = c >> 3;
        const int cb  = c & 7;
        const int col8 = ((cb ^ (row & 7)) * 8);
        gl_lds16(kp + (size_t)(b * Tt + j0 + row) * DIMd + h * HDh + col8, &smem[c * 8]);
    }

    // Q fragments straight from global (16 rows per qt, same pattern as fused_attn)
    bf16x8 qf[4][2];
    float linv[4];
#pragma unroll
    for (int qt = 0; qt < 4; ++qt) {
        const int iq = i0 + wm + qt * 16 + ln16;
        const unsigned short* qrow = qp + (size_t)(b * Tt + iq) * DIMd + h * HDh;
        qf[qt][0] = *(const bf16x8*)(qrow + qd * 8);
        qf[qt][1] = *(const bf16x8*)(qrow + 32 + qd * 8);
        linv[qt]  = 1.f / lws[(size_t)bh * Tt + iq];
    }
    __syncthreads();   // K tile resident

    const bool diag = (ti == tj);
#pragma unroll
    for (int ct = 0; ct < 4; ++ct) {
        const int krow = wn + ct * 16 + ln16;
        const bf16x8 kf0 = *(const bf16x8*)&smem[krow * 64 + ((qd ^ (krow & 7)) * 8)];
        const bf16x8 kf1 = *(const bf16x8*)&smem[krow * 64 + (((4 + qd) ^ (krow & 7)) * 8)];
#pragma unroll
        for (int qt = 0; qt < 4; ++qt) {
            floatx4 s = (floatx4){0.f, 0.f, 0.f, 0.f};
            s = __builtin_amdgcn_mfma_f32_16x16x32_bf16(kf0, qf[qt][0], s, 0, 0, 0);
            s = __builtin_amdgcn_mfma_f32_16x16x32_bf16(kf1, qf[qt][1], s, 0, 0, 0);
            const int ig = i0 + wm + qt * 16 + ln16;
            const int jb = j0 + wn + ct * 16 + qd * 4;
            const float il = linv[qt];
            float4 ev;
            if (diag) {
                ev.x = (jb + 0 <= ig) ? __expf(s[0] * NSCALE) * il : 0.f;
                ev.y = (jb + 1 <= ig) ? __expf(s[1] * NSCALE) * il : 0.f;
                ev.z = (jb + 2 <= ig) ? __expf(s[2] * NSCALE) * il : 0.f;
                ev.w = (jb + 3 <= ig) ? __expf(s[3] * NSCALE) * il : 0.f;
            } else {
                ev.x = __expf(s[0] * NSCALE) * il;
                ev.y = __expf(s[1] * NSCALE) * il;
                ev.z = __expf(s[2] * NSCALE) * il;
                ev.w = __expf(s[3] * NSCALE) * il;
            }
            *(float4*)(abase + (size_t)ig * Tt + jb) = ev;
        }
    }
}

extern "C" void kernel_launch(void* const* d_in, const int* in_sizes, int n_in,
                              void* d_out, int out_size, void* d_ws, size_t ws_size,
                              hipStream_t stream) {
    const float* Q  = (const float*)d_in[0];
    const float* K  = (const float*)d_in[1];
    const float* V  = (const float*)d_in[2];
    const float* Wq = (const float*)d_in[3];
    const float* Wk = (const float*)d_in[4];
    const float* Wv = (const float*)d_in[5];
    const float* Wo = (const float*)d_in[6];

    const size_t nytok = (size_t)Bb * Tt * DIMd;   // 4,194,304
    const size_t nw    = (size_t)DIMd * DIMd;      // 1,048,576
    float* y   = (float*)d_out;
    float* att = y + nytok;

    char* w = (char*)d_ws;
    unsigned short* qp  = (unsigned short*)w;    w += nytok * 2;   // bf16 Q-proj
    unsigned short* kp  = (unsigned short*)w;    w += nytok * 2;   // bf16 K-proj
    unsigned short* vt  = (unsigned short*)w;    w += nytok * 2;   // bf16 V-proj, TRANSPOSED [DIM][B*T]
    unsigned short* Qb  = (unsigned short*)w;    w += nytok * 2;   // reused as ymid_b
    unsigned short* Kb  = (unsigned short*)w;    w += nytok * 2;
    unsigned short* Vb  = (unsigned short*)w;    w += nytok * 2;
    unsigned short* Wqb = (unsigned short*)w;    w += nw * 2;
    unsigned short* Wkb = (unsigned short*)w;    w += nw * 2;
    unsigned short* Wvb = (unsigned short*)w;    w += nw * 2;
    unsigned short* Wob = (unsigned short*)w;    w += nw * 2;
    float* lws = (float*)w;
    unsigned short* ymid_b = Qb;

    cvt_all<<<16384, 256, 0, stream>>>(Q, K, V, Wq, Wk, Wv, Wo,
                                       Qb, Kb, Vb, Wqb, Wkb, Wvb, Wob);

    gemm_proj3<<<768, 256, 0, stream>>>(Qb, Wqb, qp, Kb, Wkb, kp, Vb, Wvb, vt);

    fused_attn<<<32 * 32, 256, 0, stream>>>(qp, kp, vt, ymid_b, lws);

    gemm_o_attw<<<256 + 8192, 256, 0, stream>>>(ymid_b, Wob, y, qp, kp, lws, att);
}